// Round 8
// baseline (37.704 us; speedup 1.0000x reference)
//
#include <hip/hip_runtime.h>

// Problem constants
#define BB 256
#define GG 16
#define LL 16
#define CC 8192
#define KK 8
// GAMMA_NEG=4, GAMMA_POS=1, CLIP=0.05, EPS=1e-8

typedef float f32x4 __attribute__((ext_vector_type(4)));

#define NBLK (GG * BB)            // 4096
#define NGRP 64                   // payload/counter groups, one 128B line each
#define FIXSCALE 1048576.0f       // 2^20 fixed-point scale

__device__ __forceinline__ float sigmoid_fast(float x) {
    float u = __expf(-x);                        // v_exp_f32
    return __builtin_amdgcn_rcpf(1.0f + u);      // v_rcp_f32
}

// target==0: t = max(s-0.05,0);  f_neg = -log(1-t) * t^4   (1-t >= 0.05 > EPS)
__device__ __forceinline__ float f_neg(float x) {
    float s  = sigmoid_fast(x);
    float t  = fmaxf(s - 0.05f, 0.0f);
    float l  = __logf(1.0f - t);
    float t2 = t * t;
    return -l * (t2 * t2);
}

// target==1: f_pos = -log(max(s,eps)) * (1-s)
__device__ __forceinline__ float f_pos(float x) {
    float s = sigmoid_fast(x);
    float l = __logf(fmaxf(s, 1e-8f));
    return -l * (1.0f - s);
}

// ---------------------------------------------------------------------------
// One block per (g,b) row (4096 blocks) -- R6's proven stream, unchanged.
// Tail fused via two-level SPREAD atomics (R5 lesson: one hot line = 12ns/op
// serialized storm; here 64 payload lines + 64 counter lines + 1 tiny line):
//   payload: fixed-point i64 atomicAdd -> acc[row&63]   (64 adds per line)
//   s_waitcnt vmcnt(0): payload acknowledged before counter issues
//   cnt1[row&63]++: group-last block bumps cnt2; global-last block reads the
//   64 accs with returning atomics (coherent channel, NO fences) and reduces
//   them in fixed lane order -> bit-deterministic integer total -> out[0].
// ---------------------------------------------------------------------------
__global__ __launch_bounds__(256) void main_kernel(
    const float* __restrict__ logits, const int* __restrict__ param,
    const int* __restrict__ label, const int* __restrict__ num,
    unsigned long long* __restrict__ acc,    // [NGRP] at 128B stride
    unsigned int* __restrict__ cnt1,         // [NGRP] at 128B stride
    unsigned int* __restrict__ cnt2,         // single
    float* __restrict__ out) {
    const int row = blockIdx.x;                  // g*BB + b
    const int g   = row >> 8;
    const int b   = row & (BB - 1);
    const int tid = threadIdx.x;

    // ---- wave-0 side work: issue all small/scattered loads first ----
    int   match   = 0;
    int   corr_on = 0;
    float xg      = 0.0f;
    if (tid < 64) {
        if (tid < LL) {                          // cnt contribution
            int pv = param[b * LL + tid];
            match = (pv >= 0) && (min(pv, GG - 1) == g);
        }
        const int t  = b * LL + g;               // this block's (b,l) pair
        const int pv = param[t];                 // broadcast load
        const int n  = min(num[t], KK);
        int myc = 0;
        if (tid < KK) myc = label[t * KK + tid];
        bool dup = false;                        // min(label_bit,1) clamp
#pragma unroll
        for (int j = 0; j < KK - 1; ++j) {
            int cj = __shfl(myc, j, 64);
            dup = dup || ((j < tid) && (cj == myc));
        }
        corr_on = (pv >= 0) && (tid < n) && !dup;
        if (corr_on) {
            const int p = min(pv, GG - 1);
            xg = logits[((size_t)p * BB + b) * CC + myc];   // scattered gather
        }
    }

    // ---- main streaming pass over row (g,b): 32 KB coalesced (R6 form) ----
    const f32x4* rp = reinterpret_cast<const f32x4*>(logits) + (size_t)row * (CC / 4);
    f32x4 v[8];
#pragma unroll
    for (int i = 0; i < 8; ++i) v[i] = rp[tid + i * 256];
    float a0 = 0.0f, a1 = 0.0f, a2 = 0.0f, a3 = 0.0f;
#pragma unroll
    for (int i = 0; i < 8; ++i) {
        a0 += f_neg(v[i].x); a1 += f_neg(v[i].y);
        a2 += f_neg(v[i].z); a3 += f_neg(v[i].w);
    }
    float accv = (a0 + a1) + (a2 + a3);
#pragma unroll
    for (int off = 32; off > 0; off >>= 1) accv += __shfl_down(accv, off, 64);
    __shared__ float sm[4];
    __shared__ int last_flag;
    if ((tid & 63) == 0) sm[tid >> 6] = accv;
    if (tid == 0) last_flag = 0;
    __syncthreads();

    if (tid < 64) {
        float corr = corr_on ? (f_pos(xg) - f_neg(xg)) : 0.0f;
        int   cnt  = match;
#pragma unroll
        for (int off = 32; off > 0; off >>= 1) {
            corr += __shfl_down(corr, off, 64);
            cnt  += __shfl_down(cnt, off, 64);
        }
        if (tid == 0) {
            float rowsum  = (sm[0] + sm[1]) + (sm[2] + sm[3]);
            float partial = (float)cnt * rowsum + corr;
            const int grp = row & (NGRP - 1);
            long long fx = llrintf(partial * FIXSCALE);
            atomicAdd(&acc[grp * 16], (unsigned long long)fx);   // own 128B line
            asm volatile("s_waitcnt vmcnt(0)" ::: "memory");     // payload acked
            unsigned int o1 = atomicAdd(&cnt1[grp * 32], 1u);    // own 128B line
            if (o1 == (NBLK / NGRP) - 1) {                       // group-last
                unsigned int o2 = atomicAdd(cnt2, 1u);           // 64 touches
                if (o2 == NGRP - 1) last_flag = 1;               // global-last
            }
        }
    }
    __syncthreads();

    if (last_flag && tid < 64) {
        // coherent read of all 64 group accumulators (returning atomics)
        unsigned long long myv = atomicAdd(&acc[tid * 16], 0ull);
#pragma unroll
        for (int off = 32; off > 0; off >>= 1)
            myv += __shfl_down(myv, off, 64);     // integer: order-fixed, exact
        if (tid == 0)
            out[0] = (float)(long long)myv * (1.0f / FIXSCALE) * (1.0f / (float)BB);
    }
}

extern "C" void kernel_launch(void* const* d_in, const int* in_sizes, int n_in,
                              void* d_out, int out_size, void* d_ws, size_t ws_size,
                              hipStream_t stream) {
    const float* logits = (const float*)d_in[0];   // (G, B, C) f32
    const int*   param  = (const int*)d_in[1];     // (B, L)
    const int*   label  = (const int*)d_in[2];     // (B, L, K)
    const int*   num    = (const int*)d_in[3];     // (B, L)
    float* out = (float*)d_out;

    // workspace layout: 64 acc lines | 64 cnt1 lines | cnt2   (128B strides)
    unsigned long long* acc  = (unsigned long long*)d_ws;                  // [64*16]
    unsigned int*       cnt1 = (unsigned int*)((char*)d_ws + NGRP * 128);  // [64*32]
    unsigned int*       cnt2 = (unsigned int*)((char*)d_ws + 2 * NGRP * 128);

    hipMemsetAsync(d_ws, 0, 2 * NGRP * 128 + 128, stream);
    main_kernel<<<NBLK, 256, 0, stream>>>(logits, param, label, num,
                                          acc, cnt1, cnt2, out);
}

// Round 10
// 23.692 us; speedup vs baseline: 1.5914x; 1.5914x over previous
//
#include <hip/hip_runtime.h>

// Problem constants
#define BB 256
#define GG 16
#define LL 16
#define CC 8192
#define KK 8
// GAMMA_NEG=4, GAMMA_POS=1, CLIP=0.05, EPS=1e-8

typedef float f32x4 __attribute__((ext_vector_type(4)));

#define LN2 0.69314718055994530942f
#define LOG2E 1.44269504088896340736f

__device__ __forceinline__ float sigmoid_fast(float x) {
    float u = exp2f(-x * LOG2E);                 // e^-x ; exp2f -> v_exp_f32
    return __builtin_amdgcn_rcpf(1.0f + u);      // v_rcp_f32
}

// exact-units helpers for the <=8 correction lanes (off hot path)
__device__ __forceinline__ float f_neg(float x) {
    float s  = sigmoid_fast(x);
    float t  = fmaxf(s - 0.05f, 0.0f);           // 1-t >= 0.05 > EPS
    float l  = __log2f(1.0f - t) * LN2;
    float t2 = t * t;
    return -l * (t2 * t2);
}
__device__ __forceinline__ float f_pos(float x) {
    float s = sigmoid_fast(x);
    float l = __log2f(fmaxf(s, 1e-8f)) * LN2;
    return -l * (1.0f - s);
}

// ---------------------------------------------------------------------------
// One block per (g,b) row (4096 blocks). R8 insight: VALU-busy ~22us of the
// ~27us main kernel => compute-issue-bound. Cut WORK, not load shape:
//  1. cnt[g,b]==0 rows (~36%: E[#distinct groups per b]=10.3 of 16) are
//     skipped entirely -- ballot over the 16 param values, early out.
//  2. stream accumulates in log2 units (one ln2 multiply per row, not per
//     element) -> ~11 instrs/elem.
// Tail stays two-kernel + plain stores (R4/R5/R8: every atomic/fence fusion
// variant lost 6-110us to serialization or writeback storms).
// ---------------------------------------------------------------------------
__global__ __launch_bounds__(256) void main_kernel(
    const float* __restrict__ logits, const int* __restrict__ param,
    const int* __restrict__ label, const int* __restrict__ num,
    float* __restrict__ partial) {
    const int row  = blockIdx.x;                 // g*BB + b
    const int g    = row >> 8;
    const int b    = row & (BB - 1);
    const int tid  = threadIdx.x;
    const int lane = tid & 63;

    // ---- cnt check (every wave computes it; broadcast loads) ----
    int pv_l = (lane < LL) ? param[b * LL + lane] : -1;
    bool match = (pv_l >= 0) && (min(pv_l, GG - 1) == g);
    int cnt = __popcll(__ballot(match));
    if (cnt == 0) {                              // ~36% of rows: nothing to do
        if (tid == 0) partial[row] = 0.0f;
        return;
    }

    // ---- wave-0 side work: <=8 scattered correction gathers ----
    int   corr_on = 0;
    float xg      = 0.0f;
    if (tid < 64) {
        const int t  = b * LL + g;               // this block's (b,l) pair
        const int pv = param[t];                 // broadcast load
        const int n  = min(num[t], KK);
        int myc = 0;
        if (tid < KK) myc = label[t * KK + tid];
        bool dup = false;                        // min(label_bit,1) clamp
#pragma unroll
        for (int j = 0; j < KK - 1; ++j) {
            int cj = __shfl(myc, j, 64);
            dup = dup || ((j < tid) && (cj == myc));
        }
        corr_on = (pv >= 0) && (tid < n) && !dup;
        if (corr_on) {
            const int p = min(pv, GG - 1);
            xg = logits[((size_t)p * BB + b) * CC + myc];   // scattered gather
        }
    }

    // ---- main streaming pass over row (g,b): 32 KB coalesced ----
    const f32x4* rp = reinterpret_cast<const f32x4*>(logits) + (size_t)row * (CC / 4);
    f32x4 v[8];
#pragma unroll
    for (int i = 0; i < 8; ++i) v[i] = rp[tid + i * 256];
    float a0 = 0.0f, a1 = 0.0f, a2 = 0.0f, a3 = 0.0f;   // log2-unit chains
#pragma unroll
    for (int i = 0; i < 8; ++i) {
        {   float s = sigmoid_fast(v[i].x); float t = fmaxf(s - 0.05f, 0.0f);
            float t2 = t * t; a0 = fmaf(-__log2f(1.0f - t), t2 * t2, a0); }
        {   float s = sigmoid_fast(v[i].y); float t = fmaxf(s - 0.05f, 0.0f);
            float t2 = t * t; a1 = fmaf(-__log2f(1.0f - t), t2 * t2, a1); }
        {   float s = sigmoid_fast(v[i].z); float t = fmaxf(s - 0.05f, 0.0f);
            float t2 = t * t; a2 = fmaf(-__log2f(1.0f - t), t2 * t2, a2); }
        {   float s = sigmoid_fast(v[i].w); float t = fmaxf(s - 0.05f, 0.0f);
            float t2 = t * t; a3 = fmaf(-__log2f(1.0f - t), t2 * t2, a3); }
    }
    float accv = (a0 + a1) + (a2 + a3);
#pragma unroll
    for (int off = 32; off > 0; off >>= 1) accv += __shfl_down(accv, off, 64);
    __shared__ float sm[4];
    if ((tid & 63) == 0) sm[tid >> 6] = accv;
    __syncthreads();

    if (tid < 64) {
        float corr = corr_on ? (f_pos(xg) - f_neg(xg)) : 0.0f;
#pragma unroll
        for (int off = 32; off > 0; off >>= 1) corr += __shfl_down(corr, off, 64);
        if (tid == 0) {
            float rowsum = ((sm[0] + sm[1]) + (sm[2] + sm[3])) * LN2;
            partial[row] = (float)cnt * rowsum + corr;
        }
    }
}

// ---------------------------------------------------------------------------
// Final: reduce 4096 partials -> mean over B. Fixed-order tree: deterministic.
// ---------------------------------------------------------------------------
__global__ __launch_bounds__(1024) void reduce_kernel(
    const float* __restrict__ partial, float* __restrict__ out) {
    const f32x4 v = reinterpret_cast<const f32x4*>(partial)[threadIdx.x];
    float s = (v.x + v.y) + (v.z + v.w);
#pragma unroll
    for (int off = 32; off > 0; off >>= 1) s += __shfl_down(s, off, 64);
    __shared__ float sm[16];
    if ((threadIdx.x & 63) == 0) sm[threadIdx.x >> 6] = s;
    __syncthreads();
    if (threadIdx.x < 64) {
        float v2 = (threadIdx.x < 16) ? sm[threadIdx.x] : 0.0f;
#pragma unroll
        for (int off = 8; off > 0; off >>= 1) v2 += __shfl_down(v2, off, 64);
        if (threadIdx.x == 0) out[0] = v2 * (1.0f / (float)BB);
    }
}

extern "C" void kernel_launch(void* const* d_in, const int* in_sizes, int n_in,
                              void* d_out, int out_size, void* d_ws, size_t ws_size,
                              hipStream_t stream) {
    const float* logits = (const float*)d_in[0];   // (G, B, C) f32
    const int*   param  = (const int*)d_in[1];     // (B, L)
    const int*   label  = (const int*)d_in[2];     // (B, L, K)
    const int*   num    = (const int*)d_in[3];     // (B, L)
    float* out = (float*)d_out;
    float* partial = (float*)d_ws;                 // 4096 floats

    main_kernel<<<GG * BB, 256, 0, stream>>>(logits, param, label, num, partial);
    reduce_kernel<<<1, 1024, 0, stream>>>(partial, out);
}

// Round 11
// 22.668 us; speedup vs baseline: 1.6633x; 1.0452x over previous
//
#include <hip/hip_runtime.h>

// Problem constants
#define BB 256
#define GG 16
#define LL 16
#define CC 8192
#define KK 8
// GAMMA_NEG=4, GAMMA_POS=1, CLIP=0.05, EPS=1e-8

typedef float f32x4 __attribute__((ext_vector_type(4)));

#define LN2 0.69314718055994530942f
#define LOG2E 1.44269504088896340736f

__device__ __forceinline__ float sigmoid_fast(float x) {
    float u = exp2f(-x * LOG2E);                 // e^-x ; exp2f -> v_exp_f32
    return __builtin_amdgcn_rcpf(1.0f + u);      // v_rcp_f32
}

// exact-units helpers for the <=8 correction lanes (off hot path)
__device__ __forceinline__ float f_neg(float x) {
    float s  = sigmoid_fast(x);
    float t  = fmaxf(s - 0.05f, 0.0f);           // 1-t >= 0.05 > EPS
    float l  = __log2f(1.0f - t) * LN2;
    float t2 = t * t;
    return -l * (t2 * t2);
}
__device__ __forceinline__ float f_pos(float x) {
    float s = sigmoid_fast(x);
    float l = __log2f(fmaxf(s, 1e-8f)) * LN2;
    return -l * (1.0f - s);
}

// ---------------------------------------------------------------------------
// TWO blocks per (g,b) row (8192 blocks, 16 KB halves): R10 showed main is
// VALU-issue-bound; halving the granule halves the final-round straggler and
// cuts VGPR (4 load buffers). Skip logic per half-block (same row data =>
// consistent ballots, no skip dilution).
//  - cnt[g,b]==0 rows (~36%) skipped via ballot over 16 param values
//  - stream accumulates in log2 units; one ln2 multiply per half-row
//  - half 0 additionally does the <=8 scattered pos-correction gathers
// Tail: two-kernel + plain stores (R4/R5/R8: all atomic/fence fusions lose).
// ---------------------------------------------------------------------------
__global__ __launch_bounds__(256) void main_kernel(
    const float* __restrict__ logits, const int* __restrict__ param,
    const int* __restrict__ label, const int* __restrict__ num,
    float* __restrict__ partial) {
    const int bid  = blockIdx.x;
    const int row  = bid >> 1;                   // g*BB + b
    const int h    = bid & 1;                    // half index
    const int g    = row >> 8;
    const int b    = row & (BB - 1);
    const int tid  = threadIdx.x;
    const int lane = tid & 63;

    // ---- cnt check (every wave computes it; broadcast loads) ----
    int pv_l = (lane < LL) ? param[b * LL + lane] : -1;
    bool match = (pv_l >= 0) && (min(pv_l, GG - 1) == g);
    int cnt = __popcll(__ballot(match));
    if (cnt == 0) {                              // ~36% of rows: nothing to do
        if (tid == 0) partial[bid] = 0.0f;
        return;
    }

    // ---- half-0 wave-0 side work: <=8 scattered correction gathers ----
    int   corr_on = 0;
    float xg      = 0.0f;
    if (h == 0 && tid < 64) {
        const int t  = b * LL + g;               // this row's (b,l) pair
        const int pv = param[t];                 // broadcast load
        const int n  = min(num[t], KK);
        int myc = 0;
        if (tid < KK) myc = label[t * KK + tid];
        bool dup = false;                        // min(label_bit,1) clamp
#pragma unroll
        for (int j = 0; j < KK - 1; ++j) {
            int cj = __shfl(myc, j, 64);
            dup = dup || ((j < tid) && (cj == myc));
        }
        corr_on = (pv >= 0) && (tid < n) && !dup;
        if (corr_on) {
            const int p = min(pv, GG - 1);
            xg = logits[((size_t)p * BB + b) * CC + myc];   // scattered gather
        }
    }

    // ---- streaming pass over half-row: 16 KB coalesced ----
    const f32x4* rp = reinterpret_cast<const f32x4*>(logits)
                      + (size_t)row * (CC / 4) + h * (CC / 8);
    f32x4 v[4];
#pragma unroll
    for (int i = 0; i < 4; ++i) v[i] = rp[tid + i * 256];
    float a0 = 0.0f, a1 = 0.0f, a2 = 0.0f, a3 = 0.0f;   // log2-unit chains
#pragma unroll
    for (int i = 0; i < 4; ++i) {
        {   float s = sigmoid_fast(v[i].x); float t = fmaxf(s - 0.05f, 0.0f);
            float t2 = t * t; a0 = fmaf(-__log2f(1.0f - t), t2 * t2, a0); }
        {   float s = sigmoid_fast(v[i].y); float t = fmaxf(s - 0.05f, 0.0f);
            float t2 = t * t; a1 = fmaf(-__log2f(1.0f - t), t2 * t2, a1); }
        {   float s = sigmoid_fast(v[i].z); float t = fmaxf(s - 0.05f, 0.0f);
            float t2 = t * t; a2 = fmaf(-__log2f(1.0f - t), t2 * t2, a2); }
        {   float s = sigmoid_fast(v[i].w); float t = fmaxf(s - 0.05f, 0.0f);
            float t2 = t * t; a3 = fmaf(-__log2f(1.0f - t), t2 * t2, a3); }
    }
    float accv = (a0 + a1) + (a2 + a3);
#pragma unroll
    for (int off = 32; off > 0; off >>= 1) accv += __shfl_down(accv, off, 64);
    __shared__ float sm[4];
    if ((tid & 63) == 0) sm[tid >> 6] = accv;
    __syncthreads();

    if (tid < 64) {
        float corr = corr_on ? (f_pos(xg) - f_neg(xg)) : 0.0f;
#pragma unroll
        for (int off = 32; off > 0; off >>= 1) corr += __shfl_down(corr, off, 64);
        if (tid == 0) {
            float halfsum = ((sm[0] + sm[1]) + (sm[2] + sm[3])) * LN2;
            partial[bid] = (float)cnt * halfsum + corr;
        }
    }
}

// ---------------------------------------------------------------------------
// Final: reduce 8192 partials -> mean over B. Fixed-order tree: deterministic.
// ---------------------------------------------------------------------------
__global__ __launch_bounds__(1024) void reduce_kernel(
    const float* __restrict__ partial, float* __restrict__ out) {
    const f32x4 v0 = reinterpret_cast<const f32x4*>(partial)[threadIdx.x];
    const f32x4 v1 = reinterpret_cast<const f32x4*>(partial)[threadIdx.x + 1024];
    float s = ((v0.x + v0.y) + (v0.z + v0.w)) + ((v1.x + v1.y) + (v1.z + v1.w));
#pragma unroll
    for (int off = 32; off > 0; off >>= 1) s += __shfl_down(s, off, 64);
    __shared__ float sm[16];
    if ((threadIdx.x & 63) == 0) sm[threadIdx.x >> 6] = s;
    __syncthreads();
    if (threadIdx.x < 64) {
        float v2 = (threadIdx.x < 16) ? sm[threadIdx.x] : 0.0f;
#pragma unroll
        for (int off = 8; off > 0; off >>= 1) v2 += __shfl_down(v2, off, 64);
        if (threadIdx.x == 0) out[0] = v2 * (1.0f / (float)BB);
    }
}

extern "C" void kernel_launch(void* const* d_in, const int* in_sizes, int n_in,
                              void* d_out, int out_size, void* d_ws, size_t ws_size,
                              hipStream_t stream) {
    const float* logits = (const float*)d_in[0];   // (G, B, C) f32
    const int*   param  = (const int*)d_in[1];     // (B, L)
    const int*   label  = (const int*)d_in[2];     // (B, L, K)
    const int*   num    = (const int*)d_in[3];     // (B, L)
    float* out = (float*)d_out;
    float* partial = (float*)d_ws;                 // 8192 floats

    main_kernel<<<2 * GG * BB, 256, 0, stream>>>(logits, param, label, num, partial);
    reduce_kernel<<<1, 1024, 0, stream>>>(partial, out);
}

// Round 12
// 22.660 us; speedup vs baseline: 1.6639x; 1.0003x over previous
//
#include <hip/hip_runtime.h>

// Problem constants
#define BB 256
#define GG 16
#define LL 16
#define CC 8192
#define KK 8
// GAMMA_NEG=4, GAMMA_POS=1, CLIP=0.05, EPS=1e-8

typedef float f32x4 __attribute__((ext_vector_type(4)));

#define LN2 0.69314718055994530942f
#define LOG2E 1.44269504088896340736f

__device__ __forceinline__ float sigmoid_fast(float x) {
    float u = exp2f(-x * LOG2E);                 // e^-x ; exp2f -> v_exp_f32
    return __builtin_amdgcn_rcpf(1.0f + u);      // v_rcp_f32
}

// exact-units helpers for the <=8 correction lanes (off hot path)
__device__ __forceinline__ float f_neg(float x) {
    float s  = sigmoid_fast(x);
    float t  = fmaxf(s - 0.05f, 0.0f);           // 1-t >= 0.05 > EPS
    float l  = __log2f(1.0f - t) * LN2;
    float t2 = t * t;
    return -l * (t2 * t2);
}
__device__ __forceinline__ float f_pos(float x) {
    float s = sigmoid_fast(x);
    float l = __log2f(fmaxf(s, 1e-8f)) * LN2;
    return -l * (1.0f - s);
}

// ---------------------------------------------------------------------------
// TWO blocks per (g,b) row (8192 blocks, 16 KB halves). R10/R11: VALU-issue
// bound. R12 lever: express the non-trans arithmetic as ext-vector ops so the
// backend emits packed fp32 (v_pk_fma_f32 / v_pk_mul_f32 / v_pk_add_f32,
// CDNA2+) -- halves the plain-VALU pipe cost; exp/rcp/log stay scalar on the
// trans pipe. Same ops per chain, same association => bit-identical result.
//  - cnt[g,b]==0 rows (~36%) skipped via ballot over 16 param values
//  - stream accumulates in log2 units; one ln2 multiply per half-row
//  - half 0 additionally does the <=8 scattered pos-correction gathers
// Tail: two-kernel + plain stores (R4/R5/R8: all atomic/fence fusions lose).
// ---------------------------------------------------------------------------
__global__ __launch_bounds__(256) void main_kernel(
    const float* __restrict__ logits, const int* __restrict__ param,
    const int* __restrict__ label, const int* __restrict__ num,
    float* __restrict__ partial) {
    const int bid  = blockIdx.x;
    const int row  = bid >> 1;                   // g*BB + b
    const int h    = bid & 1;                    // half index
    const int g    = row >> 8;
    const int b    = row & (BB - 1);
    const int tid  = threadIdx.x;
    const int lane = tid & 63;

    // ---- cnt check (every wave computes it; broadcast loads) ----
    int pv_l = (lane < LL) ? param[b * LL + lane] : -1;
    bool match = (pv_l >= 0) && (min(pv_l, GG - 1) == g);
    int cnt = __popcll(__ballot(match));
    if (cnt == 0) {                              // ~36% of rows: nothing to do
        if (tid == 0) partial[bid] = 0.0f;
        return;
    }

    // ---- half-0 wave-0 side work: <=8 scattered correction gathers ----
    int   corr_on = 0;
    float xg      = 0.0f;
    if (h == 0 && tid < 64) {
        const int t  = b * LL + g;               // this row's (b,l) pair
        const int pv = param[t];                 // broadcast load
        const int n  = min(num[t], KK);
        int myc = 0;
        if (tid < KK) myc = label[t * KK + tid];
        bool dup = false;                        // min(label_bit,1) clamp
#pragma unroll
        for (int j = 0; j < KK - 1; ++j) {
            int cj = __shfl(myc, j, 64);
            dup = dup || ((j < tid) && (cj == myc));
        }
        corr_on = (pv >= 0) && (tid < n) && !dup;
        if (corr_on) {
            const int p = min(pv, GG - 1);
            xg = logits[((size_t)p * BB + b) * CC + myc];   // scattered gather
        }
    }

    // ---- streaming pass over half-row: 16 KB coalesced, packed f32 math ----
    const f32x4* rp = reinterpret_cast<const f32x4*>(logits)
                      + (size_t)row * (CC / 4) + h * (CC / 8);
    f32x4 v[4];
#pragma unroll
    for (int i = 0; i < 4; ++i) v[i] = rp[tid + i * 256];
    f32x4 acc = {0.0f, 0.0f, 0.0f, 0.0f};        // 4 indep chains (log2 units)
#pragma unroll
    for (int i = 0; i < 4; ++i) {
        f32x4 x = v[i];
        f32x4 m = x * (-LOG2E);                  // v_pk_mul_f32 x2
        f32x4 u = {exp2f(m.x), exp2f(m.y), exp2f(m.z), exp2f(m.w)};  // trans x4
        f32x4 d = u + 1.0f;                      // v_pk_add_f32 x2
        f32x4 w = {__builtin_amdgcn_rcpf(d.x), __builtin_amdgcn_rcpf(d.y),
                   __builtin_amdgcn_rcpf(d.z), __builtin_amdgcn_rcpf(d.w)};
        f32x4 t = w - 0.05f;                     // v_pk_add_f32 x2
        t = __builtin_elementwise_max(t, (f32x4){0.0f, 0.0f, 0.0f, 0.0f});
        f32x4 e = 1.0f - t;                      // v_pk_add_f32 x2 (neg mod)
        f32x4 lg = {__log2f(e.x), __log2f(e.y), __log2f(e.z), __log2f(e.w)};
        f32x4 t2 = t * t;                        // v_pk_mul_f32 x2
        f32x4 t4 = t2 * t2;                      // v_pk_mul_f32 x2
        acc = __builtin_elementwise_fma(-lg, t4, acc);   // v_pk_fma_f32 x2
    }
    float accv = (acc.x + acc.y) + (acc.z + acc.w);
#pragma unroll
    for (int off = 32; off > 0; off >>= 1) accv += __shfl_down(accv, off, 64);
    __shared__ float sm[4];
    if ((tid & 63) == 0) sm[tid >> 6] = accv;
    __syncthreads();

    if (tid < 64) {
        float corr = corr_on ? (f_pos(xg) - f_neg(xg)) : 0.0f;
#pragma unroll
        for (int off = 32; off > 0; off >>= 1) corr += __shfl_down(corr, off, 64);
        if (tid == 0) {
            float halfsum = ((sm[0] + sm[1]) + (sm[2] + sm[3])) * LN2;
            partial[bid] = (float)cnt * halfsum + corr;
        }
    }
}

// ---------------------------------------------------------------------------
// Final: reduce 8192 partials -> mean over B. Fixed-order tree: deterministic.
// ---------------------------------------------------------------------------
__global__ __launch_bounds__(1024) void reduce_kernel(
    const float* __restrict__ partial, float* __restrict__ out) {
    const f32x4 v0 = reinterpret_cast<const f32x4*>(partial)[threadIdx.x];
    const f32x4 v1 = reinterpret_cast<const f32x4*>(partial)[threadIdx.x + 1024];
    float s = ((v0.x + v0.y) + (v0.z + v0.w)) + ((v1.x + v1.y) + (v1.z + v1.w));
#pragma unroll
    for (int off = 32; off > 0; off >>= 1) s += __shfl_down(s, off, 64);
    __shared__ float sm[16];
    if ((threadIdx.x & 63) == 0) sm[threadIdx.x >> 6] = s;
    __syncthreads();
    if (threadIdx.x < 64) {
        float v2 = (threadIdx.x < 16) ? sm[threadIdx.x] : 0.0f;
#pragma unroll
        for (int off = 8; off > 0; off >>= 1) v2 += __shfl_down(v2, off, 64);
        if (threadIdx.x == 0) out[0] = v2 * (1.0f / (float)BB);
    }
}

extern "C" void kernel_launch(void* const* d_in, const int* in_sizes, int n_in,
                              void* d_out, int out_size, void* d_ws, size_t ws_size,
                              hipStream_t stream) {
    const float* logits = (const float*)d_in[0];   // (G, B, C) f32
    const int*   param  = (const int*)d_in[1];     // (B, L)
    const int*   label  = (const int*)d_in[2];     // (B, L, K)
    const int*   num    = (const int*)d_in[3];     // (B, L)
    float* out = (float*)d_out;
    float* partial = (float*)d_ws;                 // 8192 floats

    main_kernel<<<2 * GG * BB, 256, 0, stream>>>(logits, param, label, num, partial);
    reduce_kernel<<<1, 1024, 0, stream>>>(partial, out);
}